// Round 1
// 108.918 us; speedup vs baseline: 1.0834x; 1.0834x over previous
//
#include <hip/hip_runtime.h>

#define BATCH 32
#define SEQ 4096
#define DMODEL 256
#define NCLS 5

typedef short          s8v  __attribute__((ext_vector_type(8)));  // 8 bf16 frag
typedef unsigned short u8v  __attribute__((ext_vector_type(8)));
typedef unsigned short u4v  __attribute__((ext_vector_type(4)));
typedef float          f4v  __attribute__((ext_vector_type(4)));  // C/D frag

__device__ __forceinline__ unsigned short f2b(float f) {  // RNE fp32->bf16
    unsigned u = __float_as_uint(f);
    u += 0x7FFFu + ((u >> 16) & 1u);
    return (unsigned short)(u >> 16);
}
// DPP row_shr within 16-lane rows, 0-fill (bound_ctrl) -- rows align with m16
__device__ __forceinline__ float dpp_shr4(float v) {
    return __int_as_float(__builtin_amdgcn_update_dpp(
        0, __float_as_int(v), 0x114, 0xF, 0xF, true));
}
__device__ __forceinline__ float dpp_shr8(float v) {
    return __int_as_float(__builtin_amdgcn_update_dpp(
        0, __float_as_int(v), 0x118, 0xF, 0xF, true));
}
// ds_swizzle BitMode: lane -> lane|12 (broadcast chunk-3 lane of each 4-group)
__device__ __forceinline__ float swz_or12(float v) {
    return __int_as_float(__builtin_amdgcn_ds_swizzle(
        __float_as_int(v), 0x019F));
}

// One block per channel d, 8 waves. Wave wid owns batches wid*4..wid*4+3 for
// the whole sequence: MFMA column m16 -> (b = wid*4 + (m16&3), chunk = m16>>2).
// All LDS traffic in the main loop is wave-private (cols pcol=wid*16+m16) ->
// ZERO __syncthreads in the 16-group loop. Per group (256 timesteps):
//   B: XA'[n,col] = MA'[n,j] * Xb[j,col] + cQ     (MA'[n][j] = Pn*A^{63-j},
//      C-in = cq so v = Pn*XA + cQ directly)
//   scan: 4-chunk prefix in-wave via DPP row_shr4/8 (chunks live in lanes
//      m16>>2): e = t1 + a*t2 (exact exclusive), incl = v + a*e;
//      sigma0' = a^4*sigma0 + bcast(incl@c=3); Sig snapshot = e + a^c*sigma0
//   D: y = CAT x Sig + TG x Xb   (C-in = Hcp; Dw*x folded into TG diagonal)
//      -> gelu -> per-lane pool, reduced per-wave via shfl_xor at the end.
// MFMA 16x16x32 bf16 layouts (verified m89/m91): A[m=lane&15][k=quad*8+j],
// B[k=quad*8+j][n=lane&15], D: col=lane&15, row=quad*4+reg.
__global__ __launch_bounds__(512) void ssm_mfma_kernel(
    const float* __restrict__ x,      // [B, T]
    const float* __restrict__ w_in,   // [D]
    const float* __restrict__ b_in,   // [D]
    const float* __restrict__ A_diag, // [D, 64]
    const float* __restrict__ B_in,   // [D, 64]
    const float* __restrict__ C_out,  // [D, 64]
    const float* __restrict__ D_skip, // [D]
    float* __restrict__ pooled)       // [B, 2D]
{
    __shared__ float          Pow [65 * 64];   // Pow[m*64+n] = A_n^m
    __shared__ unsigned short MAb [64 * 72];
    __shared__ unsigned short CATb[64 * 72];
    __shared__ unsigned short TGb [64 * 72];
    __shared__ unsigned short Xb  [128 * 72];
    __shared__ unsigned short Sigb[128 * 72];
    __shared__ float Pf[64], Qf[64], Gf[64], Hf[64], HcpS[64], Anf[64];

    const int tid  = threadIdx.x;
    const int lane = tid & 63;
    const int wid  = tid >> 6;
    const int m16  = lane & 15;
    const int q    = lane >> 4;
    const int q4   = q * 4;
    const int q8   = q * 8;
    const int d    = blockIdx.x;

    const float wd = w_in[d], bd = b_in[d];
    const float Dw = D_skip[d] * wd;
    const float Db = D_skip[d] * bd;

    // lane's (batch, chunk-in-group) and private LDS column
    const int bcol = wid * 4 + (m16 & 3);
    const int cch  = m16 >> 2;
    const int pcol = wid * 16 + m16;
    const float* xrow = x + bcol * SEQ + cch * 64 + q * 16;
    unsigned short* xdst = &Xb[pcol * 72 + q * 16];

    // issue group-0 stage loads immediately; setup hides the latency
    float4 xl0 = ((const float4*)xrow)[0];
    float4 xl1 = ((const float4*)xrow)[1];
    float4 xl2 = ((const float4*)xrow)[2];
    float4 xl3 = ((const float4*)xrow)[3];

    // ---- setup 1: per-n tables + power table (wave 0) ----
    if (tid < 64) {
        const int n = tid;
        const float An = A_diag[d * 64 + n];
        const float CB = B_in[d * 64 + n] * C_out[d * 64 + n];
        Anf[n] = An; Pf[n] = CB * wd; Qf[n] = CB * bd;
        float p = 1.0f;
        for (int m = 0; m <= 64; ++m) { Pow[m * 64 + n] = p; p *= An; }
    }
    __syncthreads();
    // ---- setup 2: G/H = Pow x {P,Q} matvec, 8 threads per row ----
    {
        const int mrow = tid >> 3, p8 = (tid & 7) * 8;
        float g = 0.0f, h = 0.0f;
        #pragma unroll
        for (int jj = 0; jj < 8; ++jj) {
            const float pw = Pow[mrow * 64 + p8 + jj];
            g = fmaf(pw, Pf[p8 + jj], g);
            h = fmaf(pw, Qf[p8 + jj], h);
        }
        g += __shfl_xor(g, 1, 64); g += __shfl_xor(g, 2, 64); g += __shfl_xor(g, 4, 64);
        h += __shfl_xor(h, 1, 64); h += __shfl_xor(h, 2, 64); h += __shfl_xor(h, 4, 64);
        if ((tid & 7) == 0) { Gf[mrow] = g; Hf[mrow] = h; }
    }
    __syncthreads();
    // ---- setup 3: MA'/CAT/TG matrices + Hcp prefix (shfl scan) ----
    {
        const int r0 = tid >> 3, c0 = (tid & 7) * 8;
        #pragma unroll
        for (int jj = 0; jj < 8; ++jj) {
            const int j = c0 + jj;
            MAb [r0 * 72 + j] = f2b(Pf[r0] * Pow[(63 - j) * 64 + r0]);
            CATb[r0 * 72 + j] = f2b(Pow[(r0 + 1) * 64 + j]);
            TGb [r0 * 72 + j] = (j < r0)  ? f2b(Gf[r0 - j])
                              : (j == r0) ? f2b(Gf[0] + Dw)   // Dw*x folded in
                                          : (unsigned short)0;
        }
        if (tid < 64) {
            float v = Hf[tid];
            #pragma unroll
            for (int dl = 1; dl < 64; dl <<= 1) {
                const float t = __shfl(v, (tid - dl) & 63, 64);
                v += (tid >= dl) ? t : 0.0f;
            }
            HcpS[tid] = v + Db;
        }
    }
    __syncthreads();

    // ---- loop-invariant registers (frags park in unified AGPR file) ----
    s8v aMA[4][2], aCAT[4][2], aTG[4][2];
    #pragma unroll
    for (int rt = 0; rt < 4; ++rt)
        #pragma unroll
        for (int kb = 0; kb < 2; ++kb) {
            const int off = (rt * 16 + m16) * 72 + kb * 32 + q8;
            aMA [rt][kb] = *(const s8v*)&MAb [off];
            aCAT[rt][kb] = *(const s8v*)&CATb[off];
            aTG [rt][kb] = *(const s8v*)&TGb [off];
        }
    f4v cq[4], hcp[4];
    float a64v[4][4], sig0[4][4];
    #pragma unroll
    for (int rt = 0; rt < 4; ++rt)
        #pragma unroll
        for (int r = 0; r < 4; ++r) {
            const int nn = rt * 16 + q4 + r;
            const float A64 = Pow[64 * 64 + nn];
            a64v[rt][r] = A64;
            cq[rt][r]   = Qf[nn] * (1.0f - A64) / (1.0f - Anf[nn]);
            hcp[rt][r]  = HcpS[nn];
            sig0[rt][r] = 0.0f;
        }
    const bool cc1 = (cch & 1) != 0;
    const bool cc2 = (cch & 2) != 0;

    // ---- prologue: stage group 0 (wave-private cols) ----
    {
        u8v lo, hi;
        lo[0]=f2b(xl0.x); lo[1]=f2b(xl0.y); lo[2]=f2b(xl0.z); lo[3]=f2b(xl0.w);
        lo[4]=f2b(xl1.x); lo[5]=f2b(xl1.y); lo[6]=f2b(xl1.z); lo[7]=f2b(xl1.w);
        hi[0]=f2b(xl2.x); hi[1]=f2b(xl2.y); hi[2]=f2b(xl2.z); hi[3]=f2b(xl2.w);
        hi[4]=f2b(xl3.x); hi[5]=f2b(xl3.y); hi[6]=f2b(xl3.z); hi[7]=f2b(xl3.w);
        *(u8v*)xdst       = lo;
        *(u8v*)(xdst + 8) = hi;
    }

    float psum = 0.0f, pmax = -1e30f;

    #pragma unroll 1
    for (int g = 0; g < 16; ++g) {
        // issue-early loads for group g+1 (complete under this body)
        float4 yl0, yl1, yl2, yl3;
        if (g < 15) {
            const float4* xg = (const float4*)(xrow + (g + 1) * 256);
            yl0 = xg[0]; yl1 = xg[1]; yl2 = xg[2]; yl3 = xg[3];
        }
        // ---- B: v = cq + MA' x Xb ----
        const s8v bx0 = *(const s8v*)&Xb[pcol * 72 + q8];
        const s8v bx1 = *(const s8v*)&Xb[pcol * 72 + 32 + q8];
        f4v vB[4];
        #pragma unroll
        for (int rt = 0; rt < 4; ++rt) {
            vB[rt] = __builtin_amdgcn_mfma_f32_16x16x32_bf16(aMA[rt][0], bx0, cq[rt], 0, 0, 0);
            vB[rt] = __builtin_amdgcn_mfma_f32_16x16x32_bf16(aMA[rt][1], bx1, vB[rt], 0, 0, 0);
        }
        // stage write for g+1 (bx already consumed into regs; same-wave cols)
        if (g < 15) {
            u8v lo, hi;
            lo[0]=f2b(yl0.x); lo[1]=f2b(yl0.y); lo[2]=f2b(yl0.z); lo[3]=f2b(yl0.w);
            lo[4]=f2b(yl1.x); lo[5]=f2b(yl1.y); lo[6]=f2b(yl1.z); lo[7]=f2b(yl1.w);
            hi[0]=f2b(yl2.x); hi[1]=f2b(yl2.y); hi[2]=f2b(yl2.z); hi[3]=f2b(yl2.w);
            hi[4]=f2b(yl3.x); hi[5]=f2b(yl3.y); hi[6]=f2b(yl3.z); hi[7]=f2b(yl3.w);
            *(u8v*)xdst       = lo;
            *(u8v*)(xdst + 8) = hi;
        }
        // ---- in-wave 4-chunk scan (DPP) + Sig snapshot ----
        #pragma unroll
        for (int rt = 0; rt < 4; ++rt) {
            u4v sg;
            #pragma unroll
            for (int r = 0; r < 4; ++r) {
                const float a  = a64v[rt][r];
                const float a2 = a * a;
                const float v  = vB[rt][r];
                const float t1 = dpp_shr4(v);            // v@(c-1), 0 at c=0
                const float i1 = fmaf(a, t1, v);
                const float t2 = dpp_shr8(i1);           // incl1@(c-2), 0 at c<2
                const float e  = fmaf(a, t2, t1);        // exact exclusive prefix
                const float ac = (cc1 ? a : 1.0f) * (cc2 ? a2 : 1.0f);  // a^c
                const float se = fmaf(ac, sig0[rt][r], e);   // entering state
                const float i2 = fmaf(a, e, v);          // inclusive prefix
                const float S  = swz_or12(i2);           // broadcast c=3 lane
                sig0[rt][r] = fmaf(a2 * a2, sig0[rt][r], S);
                sg[r] = f2b(se);
            }
            *(u4v*)&Sigb[pcol * 72 + rt * 16 + q4] = sg;
        }
        // ---- D: y = Hcp + CAT x Sig + TG x Xb -> gelu -> pool ----
        const s8v bs0 = *(const s8v*)&Sigb[pcol * 72 + q8];
        const s8v bs1 = *(const s8v*)&Sigb[pcol * 72 + 32 + q8];
        #pragma unroll
        for (int rt = 0; rt < 4; ++rt) {
            f4v acc = __builtin_amdgcn_mfma_f32_16x16x32_bf16(aCAT[rt][0], bs0, hcp[rt], 0, 0, 0);
            acc = __builtin_amdgcn_mfma_f32_16x16x32_bf16(aCAT[rt][1], bs1, acc, 0, 0, 0);
            acc = __builtin_amdgcn_mfma_f32_16x16x32_bf16(aTG [rt][0], bx0, acc, 0, 0, 0);
            acc = __builtin_amdgcn_mfma_f32_16x16x32_bf16(aTG [rt][1], bx1, acc, 0, 0, 0);
            #pragma unroll
            for (int r = 0; r < 4; ++r) {
                const float yt = acc[r];
                const float y2 = yt * yt;
                const float zn = yt * fmaf(-0.07135481627f, y2, -1.5957691216f);
                const float h  = yt * __builtin_amdgcn_rcpf(1.0f + __expf(zn));
                psum += h;
                pmax = fmaxf(pmax, h);
            }
        }
    }

    // ---- pool finalize: wave owns its 4 batches; reduce lanes sharing lane&3
    #pragma unroll
    for (int dl = 4; dl <= 32; dl <<= 1) {
        psum += __shfl_xor(psum, dl, 64);
        pmax  = fmaxf(pmax, __shfl_xor(pmax, dl, 64));
    }
    if (lane < 4) {
        const int b = wid * 4 + lane;
        pooled[b * (2 * DMODEL) + d]          = psum * (1.0f / SEQ);
        pooled[b * (2 * DMODEL) + DMODEL + d] = pmax;
    }
}

// out[b,c] = pooled[b,:] @ W_head[:,c] + b_head[c]; one wave per batch row
__global__ __launch_bounds__(64) void head_kernel(
    const float* __restrict__ pooled,
    const float* __restrict__ W_head,
    const float* __restrict__ b_head,
    float* __restrict__ out)
{
    const int b = blockIdx.x, l = threadIdx.x;
    const float* p = pooled + b * (2 * DMODEL);
    float acc[NCLS] = {0, 0, 0, 0, 0};
    for (int k = l; k < 2 * DMODEL; k += 64) {
        const float pv = p[k];
        #pragma unroll
        for (int c = 0; c < NCLS; ++c)
            acc[c] = fmaf(pv, W_head[k * NCLS + c], acc[c]);
    }
    #pragma unroll
    for (int off = 32; off; off >>= 1)
        #pragma unroll
        for (int c = 0; c < NCLS; ++c) acc[c] += __shfl_xor(acc[c], off, 64);
    if (l == 0)
        #pragma unroll
        for (int c = 0; c < NCLS; ++c) out[b * NCLS + c] = acc[c] + b_head[c];
}

extern "C" void kernel_launch(void* const* d_in, const int* in_sizes, int n_in,
                              void* d_out, int out_size, void* d_ws, size_t ws_size,
                              hipStream_t stream) {
    const float* x      = (const float*)d_in[0];
    const float* w_in   = (const float*)d_in[1];
    const float* b_in   = (const float*)d_in[2];
    const float* A_diag = (const float*)d_in[3];
    const float* B_in   = (const float*)d_in[4];
    const float* C_out  = (const float*)d_in[5];
    const float* D_skip = (const float*)d_in[6];
    const float* W_head = (const float*)d_in[7];
    const float* b_head = (const float*)d_in[8];
    float* pooled = (float*)d_ws;   // 32*512*4 = 64 KB scratch
    float* out    = (float*)d_out;

    ssm_mfma_kernel<<<DMODEL, 512, 0, stream>>>(x, w_in, b_in, A_diag, B_in,
                                                C_out, D_skip, pooled);
    head_kernel<<<BATCH, 64, 0, stream>>>(pooled, W_head, b_head, out);
}